// Round 6
// baseline (805.419 us; speedup 1.0000x reference)
//
#include <hip/hip_runtime.h>
#include <math.h>

#define V 50257
#define D 1024
#define C 131072
#define SMOOTH 32.0f

// clang-native float4 (ext_vector_type) — required for __builtin_nontemporal_load
typedef float fx4 __attribute__((ext_vector_type(4)));

// ---------------------------------------------------------------------------
// Kernel 1: one 64-lane wave per cache element.
//   ssq = sum_d (cache_h[i][d] - h_t[w][d])^2   (float4 loads, 16B/lane)
//   atomicAdd(p[w], exp(sqrt(ssq)/SMOOTH))
// cache_h is streamed exactly once -> non-temporal loads (keep L2/L3 for the
// h_t gather, which has ~2.6x reuse and fits Infinity Cache).
// Block = 256 threads = 4 waves -> 4 elements/block, grid = C/4.
// ---------------------------------------------------------------------------
__global__ __launch_bounds__(256) void k_scatter(
    const float* __restrict__ h_t,
    const float* __restrict__ cache_h,
    const int* __restrict__ cache_words,
    float* __restrict__ p)
{
    const int wave = threadIdx.x >> 6;
    const int lane = threadIdx.x & 63;
    const int i = (blockIdx.x << 2) + wave;          // cache element, i < C by grid sizing

    const int w = cache_words[i];
    const fx4* ch = (const fx4*)(cache_h + (size_t)i * D);
    const fx4* ht = (const fx4*)(h_t + (size_t)w * D);

    float ssq = 0.0f;
#pragma unroll
    for (int k = 0; k < 4; ++k) {
        fx4 a = __builtin_nontemporal_load(&ch[lane + (k << 6)]);  // streaming
        fx4 b = ht[lane + (k << 6)];                               // cached (reused)
        fx4 d = a - b;
        ssq += d.x * d.x + d.y * d.y + d.z * d.z + d.w * d.w;
    }
    // 64-lane butterfly reduce
#pragma unroll
    for (int off = 32; off > 0; off >>= 1)
        ssq += __shfl_xor(ssq, off, 64);

    if (lane == 0) {
        float val = expf(sqrtf(ssq) * (1.0f / SMOOTH));
        atomicAdd(&p[w], val);
    }
}

// ---------------------------------------------------------------------------
// Kernel 2: global max of p (p >= 0 so uint-ordered atomicMax is valid)
// ---------------------------------------------------------------------------
__global__ __launch_bounds__(256) void k_max(
    const float* __restrict__ p, unsigned int* __restrict__ m)
{
    float lm = 0.0f;
    for (int v = blockIdx.x * blockDim.x + threadIdx.x; v < V;
         v += gridDim.x * blockDim.x)
        lm = fmaxf(lm, p[v]);
#pragma unroll
    for (int off = 32; off > 0; off >>= 1)
        lm = fmaxf(lm, __shfl_xor(lm, off, 64));
    __shared__ float s[4];
    if ((threadIdx.x & 63) == 0) s[threadIdx.x >> 6] = lm;
    __syncthreads();
    if (threadIdx.x == 0) {
        lm = fmaxf(fmaxf(s[0], s[1]), fmaxf(s[2], s[3]));
        atomicMax(m, __float_as_uint(lm));
    }
}

// ---------------------------------------------------------------------------
// Kernel 3: S = sum_v exp(p[v] - m)
// ---------------------------------------------------------------------------
__global__ __launch_bounds__(256) void k_sumexp(
    const float* __restrict__ p, const unsigned int* __restrict__ m,
    float* __restrict__ S)
{
    const float mm = __uint_as_float(*m);
    float ls = 0.0f;
    for (int v = blockIdx.x * blockDim.x + threadIdx.x; v < V;
         v += gridDim.x * blockDim.x)
        ls += expf(p[v] - mm);
#pragma unroll
    for (int off = 32; off > 0; off >>= 1)
        ls += __shfl_xor(ls, off, 64);
    __shared__ float s[4];
    if ((threadIdx.x & 63) == 0) s[threadIdx.x >> 6] = ls;
    __syncthreads();
    if (threadIdx.x == 0)
        atomicAdd(S, s[0] + s[1] + s[2] + s[3]);
}

// ---------------------------------------------------------------------------
// Kernel 4: out[v] = p[v] - m - log(S)   (log_softmax)
// ---------------------------------------------------------------------------
__global__ __launch_bounds__(256) void k_finalize(
    const float* __restrict__ p, const unsigned int* __restrict__ m,
    const float* __restrict__ S, float* __restrict__ out)
{
    const float shift = __uint_as_float(*m) + logf(*S);
    for (int v = blockIdx.x * blockDim.x + threadIdx.x; v < V;
         v += gridDim.x * blockDim.x)
        out[v] = p[v] - shift;
}

extern "C" void kernel_launch(void* const* d_in, const int* in_sizes, int n_in,
                              void* d_out, int out_size, void* d_ws, size_t ws_size,
                              hipStream_t stream)
{
    const float* h_t         = (const float*)d_in[0];   // [V, D]
    const float* cache_h     = (const float*)d_in[1];   // [C, D]
    const int*   cache_words = (const int*)d_in[2];     // [C]
    float* out = (float*)d_out;                         // [V]

    // workspace layout: p[V] floats | m (uint) | S (float)
    float*        p = (float*)d_ws;
    unsigned int* m = (unsigned int*)((char*)d_ws + (size_t)V * sizeof(float));
    float*        S = (float*)((char*)d_ws + (size_t)V * sizeof(float) + sizeof(unsigned int));

    // zero p, m, S in one shot (graph-capture safe)
    (void)hipMemsetAsync(d_ws, 0, (size_t)V * sizeof(float) + 2 * sizeof(unsigned int), stream);

    k_scatter<<<C / 4, 256, 0, stream>>>(h_t, cache_h, cache_words, p);

    // 99 blocks * 256 threads = 25344 threads -> each covers V in <=2 iters
    k_max     <<<99, 256, 0, stream>>>(p, m);
    k_sumexp  <<<99, 256, 0, stream>>>(p, m, S);
    k_finalize<<<99, 256, 0, stream>>>(p, m, S, out);
}